// Round 14
// baseline (386.846 us; speedup 1.0000x reference)
//
#include <hip/hip_runtime.h>
#include <hip/hip_bf16.h>
#include <stdint.h>

// Problem constants (GQA: D=1024, 16 heads, 4 groups, hd=64)
#define D_MODEL 1024
#define T_LEN   2048
#define BATCH   2
#define N_HEADS 16
#define KV_DIM  256
#define QKV_N   1536              // 1024 + 256 + 256 fused projection width
#define M_ROWS  (BATCH * T_LEN)   // 4096

typedef unsigned short u16;
typedef __bf16 bf16x8 __attribute__((ext_vector_type(8)));
typedef __bf16 bf16x2 __attribute__((ext_vector_type(2)));
typedef float  f32x4  __attribute__((ext_vector_type(4)));
typedef uint32_t u32x4v __attribute__((ext_vector_type(4)));

__device__ __forceinline__ u16 f2b(float f) {
    uint32_t u = __builtin_bit_cast(uint32_t, f);
    u += 0x7FFFu + ((u >> 16) & 1u);   // round-to-nearest-even
    return (u16)(u >> 16);
}

// pack two f32 -> two bf16 in one u32 (lo = a, hi = b)
__device__ __forceinline__ uint32_t pk_bf16(float a, float b) {
#if __has_builtin(__builtin_amdgcn_cvt_pk_bf16_f32)
    bf16x2 v = __builtin_amdgcn_cvt_pk_bf16_f32(a, b);
    return __builtin_bit_cast(uint32_t, v);
#else
    return (uint32_t)f2b(a) | ((uint32_t)f2b(b) << 16);
#endif
}

// async global->LDS, 16B per lane; LDS dest = wave-uniform base + lane*16
__device__ __forceinline__ void gl_lds16(const void* g, void* l) {
    __builtin_amdgcn_global_load_lds(g, l, 16, 0, 0);
}

// Chunk table: 48 entries, LPT-ish order, boustrophedon within length tiers
// so per-CU totals balance. Encoding: value<32 -> whole strip q4=value;
// else split chunk q4=value>>1, h=value&1 (h0=[0,ceil), h1=[ceil,q4+1)).
__constant__ unsigned char LPT_TBL[48] = {
    62, 63, 60, 15, 61, 58, 59, 56,     // L=16,16,16,16,15,15,15,15
    50, 53, 13, 52, 55, 54, 57, 14,     // L=13,13,14,14,14,14,14,15 (rev)
    51, 48, 12, 49, 46, 47, 44, 11,     // L=13,13,13,12,12,12,12,12
    39, 38, 41, 10, 40, 43, 42, 45,     // L=10,10,10,11,11,11,11,11 (rev)
    36,  9, 37, 34, 35, 32,  8, 33,     // L=10,10,9,9,9,9,9,8
     0,  1,  2,  3,  4,  5,  6,  7      // L=1..8 (rev)
};

// ---------------------------------------------------------------------------
// prep: fp32->bf16 convert of x (blocks 0..2047) + all-weight transpose/cvt
// (blocks 2048..4607) + flag-zero block (4608). BUGFIX vs rounds 11/12:
// the block has 256 threads but there are 512 flags -- the old `if (tid <
// 512) flags[tid] = 0` left flags[256..511] (ALL of batch 1's split pairs)
// uninitialized on launch 1 and stale (=2) on replays -> deterministic
// wrong combine (bit-identical absmax 3.0 across runs). Now each thread
// zeroes two entries.
// ---------------------------------------------------------------------------
__global__ __launch_bounds__(256) void prep(
    const float* __restrict__ x,
    const float* __restrict__ Wq, const float* __restrict__ Wk,
    const float* __restrict__ Wv, const float* __restrict__ Wo,
    u16* __restrict__ xb, u16* __restrict__ WcatT, u16* __restrict__ WoT,
    unsigned int* __restrict__ flags)
{
    __shared__ u16 tile[32][33];
    int id = blockIdx.x;
    int tid = threadIdx.x;
    if (id == 4608) {
        flags[tid] = 0u;
        flags[tid + 256] = 0u;
        return;
    }
    if (id < 2048) {
        int i = (id * 256 + tid) * 8;
        float4 a = *(const float4*)&x[i];
        float4 c = *(const float4*)&x[i + 4];
        u16 r[8] = { f2b(a.x), f2b(a.y), f2b(a.z), f2b(a.w),
                     f2b(c.x), f2b(c.y), f2b(c.z), f2b(c.w) };
        *(uint4*)&xb[i] = *(const uint4*)r;
        return;
    }
    int t = id - 2048;
    int bx = t % 80;
    int k0 = (t / 80) * 32;
    const float* src; u16* dst; int N, n0;
    if (bx < 32)       { src = Wq; dst = WcatT;                   N = 1024; n0 = bx * 32; }
    else if (bx < 40)  { src = Wk; dst = WcatT + 1024 * 1024;     N = 256;  n0 = (bx - 32) * 32; }
    else if (bx < 48)  { src = Wv; dst = WcatT + 1280 * 1024;     N = 256;  n0 = (bx - 40) * 32; }
    else               { src = Wo; dst = WoT;                     N = 1024; n0 = (bx - 48) * 32; }
    for (int i = 0; i < 4; ++i) {
        int idx = tid + i * 256;
        int r = idx >> 5, c = idx & 31;
        tile[r][c] = f2b(src[(size_t)(k0 + r) * N + (n0 + c)]);
    }
    __syncthreads();
    for (int i = 0; i < 4; ++i) {
        int idx = tid + i * 256;
        int r = idx >> 5, c = idx & 31;   // r: n-local, c: k-local
        dst[(size_t)(n0 + r) * 1024 + (k0 + c)] = tile[c][r];
    }
}

// ---------------------------------------------------------------------------
// Fused QKV GEMM, 64x128 tile, 4 waves, SINGLE-BUFFERED (round-8 proven
// form; 8-wave, dbuf, and 128x128 variants all measured neutral/negative).
// 768 blocks = 3/CU. Q -> Qb[4096x1024] PRE-SCALED (log2 domain).
// K -> Kpack, V -> Vpack: FRAGMENT-MAJOR layouts:
//   Kpack[(b,g)][t64][kk][ntk][lane=quad*16+l15][8e]
//       = K[key = t64*64+ntk*16+l15][d = kk*32+quad*8+e]
//   Vpack[(b,g)][t64][kkp][dt][lane=quad*16+l15][8e]
//       = V[key = t64*64+kkp*32+quad*8+e][d = dt*16+l15]
// ---------------------------------------------------------------------------
__global__ __launch_bounds__(256) void gemm_qkv(
    const u16* __restrict__ A, const u16* __restrict__ BT,
    const float* __restrict__ bq, const float* __restrict__ bk,
    const float* __restrict__ bv, u16* __restrict__ Qb,
    u16* __restrict__ Kpack, u16* __restrict__ Vpack)
{
    constexpr int K = 1024;
    constexpr float SCALE = 0.125f * 1.44269504088896f;
    __shared__ __align__(16) u16 As[64 * 64];
    __shared__ __align__(16) u16 Bs[128 * 64];

    int tid  = threadIdx.x;
    int lane = tid & 63, w = tid >> 6;
    int quad = lane >> 4, l15 = lane & 15;
    int m0 = blockIdx.y * 64, n0 = blockIdx.x * 128;
    int lr = lane >> 3, lc = (lane & 7) * 8;

    f32x4 acc[4][2] = {};

    for (int k0 = 0; k0 < K; k0 += 64) {
        for (int t = 0; t < 2; ++t) {
            int rb = t * 32 + w * 8;
            gl_lds16(&A[(size_t)(m0 + rb + lr) * K + k0 + lc], &As[rb * 64]);
        }
        for (int t = 0; t < 4; ++t) {
            int rb = t * 32 + w * 8;
            gl_lds16(&BT[(size_t)(n0 + rb + lr) * K + k0 + lc], &Bs[rb * 64]);
        }
        __syncthreads();
        for (int kk = 0; kk < 64; kk += 32) {
            bf16x8 a[4], b[2];
            for (int i = 0; i < 4; ++i)
                a[i] = *(const bf16x8*)&As[(i * 16 + l15) * 64 + kk + quad * 8];
            for (int j = 0; j < 2; ++j)
                b[j] = *(const bf16x8*)&Bs[(w * 32 + j * 16 + l15) * 64 + kk + quad * 8];
            for (int i = 0; i < 4; ++i)
                for (int j = 0; j < 2; ++j)
                    acc[i][j] = __builtin_amdgcn_mfma_f32_16x16x32_bf16(
                        a[i], b[j], acc[i][j], 0, 0, 0);
        }
        __syncthreads();
    }

    for (int j = 0; j < 2; ++j) {
        int col = n0 + w * 32 + j * 16 + l15;
        float bj = (col < 1024) ? bq[col] : (col < 1280) ? bk[col - 1024] : bv[col - 1280];
        for (int i = 0; i < 4; ++i) {
            int rowb = m0 + i * 16 + quad * 4;       // 4 consecutive rows
            int bb = rowb >> 11, keyloc = rowb & 2047;
            int t64 = keyloc >> 6;
            if (col < 1024) {
                for (int r = 0; r < 4; ++r)
                    Qb[(size_t)(rowb + r) * 1024 + col] =
                        f2b((acc[i][j][r] + bj) * SCALE);
            } else if (col < 1280) {
                int d = col - 1024; int g = d >> 6; d &= 63;
                int kk = d >> 5, qd = (d >> 3) & 3, e = d & 7;
                int ntk = (keyloc >> 4) & 3, l15k = keyloc & 15;
                size_t base = ((((size_t)(bb * 4 + g) * 32 + t64) * 2 + kk) * 4
                               + ntk) * 512 + qd * 128 + l15k * 8 + e;
                for (int r = 0; r < 4; ++r)
                    Kpack[base + r * 8] = f2b(acc[i][j][r] + bj);
            } else {
                int d = col - 1280; int g = d >> 6; d &= 63;
                int dt = d >> 4, l15v = d & 15;
                int kkp = (keyloc >> 5) & 1, qv = (keyloc >> 3) & 3, e0 = keyloc & 7;
                u16 tmp[4];
                for (int r = 0; r < 4; ++r) tmp[r] = f2b(acc[i][j][r] + bj);
                size_t base = ((((size_t)(bb * 4 + g) * 32 + t64) * 2 + kkp) * 4
                               + dt) * 512 + (qv * 16 + l15v) * 8 + e0;
                *(uint64_t*)&Vpack[base] = *(const uint64_t*)tmp;
            }
        }
    }
}

// ---------------------------------------------------------------------------
// Out-proj GEMM, 64x128 tile, 4 waves, SINGLE-BUFFERED (round-8 form).
// out[M x 1024](fp32) = AO * WoT^T + bo. 512 blocks = 2/CU.
// ---------------------------------------------------------------------------
__global__ __launch_bounds__(256) void gemm_out(
    const u16* __restrict__ A, const u16* __restrict__ BT,
    const float* __restrict__ bias, float* __restrict__ C)
{
    constexpr int K = 1024, N = 1024;
    __shared__ __align__(16) u16 As[64 * 64];
    __shared__ __align__(16) u16 Bs[128 * 64];

    int tid  = threadIdx.x;
    int lane = tid & 63, w = tid >> 6;
    int quad = lane >> 4, l15 = lane & 15;
    int m0 = blockIdx.y * 64, n0 = blockIdx.x * 128;
    int lr = lane >> 3, lc = (lane & 7) * 8;

    f32x4 acc[4][2] = {};

    for (int k0 = 0; k0 < K; k0 += 64) {
        for (int t = 0; t < 2; ++t) {
            int rb = t * 32 + w * 8;
            gl_lds16(&A[(size_t)(m0 + rb + lr) * K + k0 + lc], &As[rb * 64]);
        }
        for (int t = 0; t < 4; ++t) {
            int rb = t * 32 + w * 8;
            gl_lds16(&BT[(size_t)(n0 + rb + lr) * K + k0 + lc], &Bs[rb * 64]);
        }
        __syncthreads();
        for (int kk = 0; kk < 64; kk += 32) {
            bf16x8 a[4], b[2];
            for (int i = 0; i < 4; ++i)
                a[i] = *(const bf16x8*)&As[(i * 16 + l15) * 64 + kk + quad * 8];
            for (int j = 0; j < 2; ++j)
                b[j] = *(const bf16x8*)&Bs[(w * 32 + j * 16 + l15) * 64 + kk + quad * 8];
            for (int i = 0; i < 4; ++i)
                for (int j = 0; j < 2; ++j)
                    acc[i][j] = __builtin_amdgcn_mfma_f32_16x16x32_bf16(
                        a[i], b[j], acc[i][j], 0, 0, 0);
        }
        __syncthreads();
    }

    for (int j = 0; j < 2; ++j) {
        int col = n0 + w * 32 + j * 16 + l15;
        float bj = bias[col];
        for (int i = 0; i < 4; ++i) {
            int rowb = m0 + i * 16 + quad * 4;
            for (int r = 0; r < 4; ++r)
                C[(size_t)(rowb + r) * N + col] = acc[i][j][r] + bj;
        }
    }
}

// ---------------------------------------------------------------------------
// Flash attention v13c (causal, GQA): v12 (chunked LPT structure + ones-MFMA
// denominator) + FUSED COMBINE. Protocol: all threads store partials ->
// __threadfence() -> __syncthreads() (all waves stored+fenced) -> tid0
// atomicAdd ticket; second-finishing block (ticket==1) fences (acquire),
// reads only the OTHER half's 4KB (own half still in registers),
// normalizes, stores AO. No spinning -> no deadlock; device-scope
// atomics/fences -> no XCD placement assumption (G16).
// Rounds 11/12 failed NOT from this protocol but from prep zeroing only
// 256 of the 512 flags (fixed above). Round 13 never ran (infra failure).
// ---------------------------------------------------------------------------
__global__ __launch_bounds__(256, 6) void attn_kernel(
    const u16* __restrict__ Qb,     // [B*T, 1024] bf16, pre-scaled
    const u16* __restrict__ Kpack,  // fragment-packed K
    const u16* __restrict__ Vpack,  // fragment-packed V
    u16* __restrict__ AO,           // [B*T, 1024] bf16
    float* __restrict__ Opart,      // [1024 partials][4 heads][16 rows][64 d]
    float* __restrict__ Lpart,      // [1024 partials][4 heads][16 rows]
    unsigned int* __restrict__ flags)  // [512] pair tickets (prep-zeroed)
{
    constexpr int LDP = 72;   // P row stride (u16)
    __shared__ __align__(16) u16 Kv[4096];          // 8KB K tile, fragment-major
    __shared__ __align__(16) u16 Vv[4096];          // 8KB V tile, fragment-major
    __shared__ __align__(16) u16 Ps[4][16 * LDP];   // wave-private P tiles
    __shared__ unsigned int ticket;

    int tid  = threadIdx.x;
    int lane = tid & 63, w = tid >> 6;              // w = head within group
    int quad = lane >> 4, l15 = lane & 15;

    int gid = blockIdx.x;
    int bg = gid & 7;
    int b = bg >> 2, g = bg & 3;
    int idx = gid >> 3;                      // 0..191
    int code = LPT_TBL[idx >> 2];
    int kq = idx & 3;
    int q4, h = 0, tgB, tgE;
    bool split;
    if (code < 32) {
        split = false; q4 = code; tgB = 0; tgE = q4 + 1;
    } else {
        split = true; q4 = code >> 1; h = code & 1;
        int nA = (q4 + 2) >> 1;              // ceil((q4+1)/2)
        tgB = h ? nA : 0;
        tgE = h ? (q4 + 1) : nA;
    }
    int j = q4 * 4 + kq;
    int head = g * 4 + w;
    int q0 = j * 16;
    int iters64 = q4 + 1;                    // total 64-key tiles of strip

    const u16* Qp = Qb + ((size_t)b * T_LEN + q0) * 1024 + head * 64;
    const u16* Kp = Kpack + (size_t)bg * 131072;
    const u16* Vp = Vpack + (size_t)bg * 131072;
    u16*       Op = AO + ((size_t)b * T_LEN + q0) * D_MODEL + head * 64;
    u16* Pw = Ps[w];

    // Q fragments (loop-invariant): B-frag Q[n=qrow][k=d], 16 rows
    bf16x8 Qfrag[2];
    #pragma unroll
    for (int kk = 0; kk < 2; ++kk)
        Qfrag[kk] = *(const bf16x8*)&Qp[(size_t)l15 * 1024 + kk * 32 + quad * 8];

    // constant all-ones bf16 B-fragment for the denominator MFMA
    u32x4v onesbits = {0x3F803F80u, 0x3F803F80u, 0x3F803F80u, 0x3F803F80u};
    bf16x8 vones = __builtin_bit_cast(bf16x8, onesbits);

    f32x4 o[4] = {};
    f32x4 o_l = {};          // o_l[r] = softmax denom for row quad*4+r
    int qrow = q0 + l15;

    for (int tg = tgB; tg < tgE; ++tg) {
        bool diag = (tg == iters64 - 1);

        // stage K+V tiles (8KB each) into LDS once for all 4 heads.
        const u16* kt = Kp + (size_t)tg * 4096;
        const u16* vt = Vp + (size_t)tg * 4096;
        #pragma unroll
        for (int c = 0; c < 2; ++c) {
            int ch = w * 2 + c;                     // 0..7
            gl_lds16(kt + ch * 512 + lane * 8, &Kv[ch * 512]);
            gl_lds16(vt + ch * 512 + lane * 8, &Vv[ch * 512]);
        }
        __syncthreads();   // staging drained (implicit vmcnt(0))

        // S^T = K * Q^T; exp2; packed P -> wave-private LDS
        f32x4 sacc[4] = {};
        #pragma unroll
        for (int kk = 0; kk < 2; ++kk) {
            bf16x8 bQ = Qfrag[kk];
            #pragma unroll
            for (int ntk = 0; ntk < 4; ++ntk) {
                bf16x8 aK = *(const bf16x8*)&Kv[(kk * 4 + ntk) * 512 + lane * 8];
                sacc[ntk] = __builtin_amdgcn_mfma_f32_16x16x32_bf16(
                    aK, bQ, sacc[ntk], 0, 0, 0);
            }
        }
        #pragma unroll
        for (int ntk = 0; ntk < 4; ++ntk) {
            float p0, p1, p2, p3;
            if (diag) {
                int key = tg * 64 + ntk * 16 + quad * 4;
                p0 = (key + 0 <= qrow) ? exp2f(sacc[ntk][0]) : 0.f;
                p1 = (key + 1 <= qrow) ? exp2f(sacc[ntk][1]) : 0.f;
                p2 = (key + 2 <= qrow) ? exp2f(sacc[ntk][2]) : 0.f;
                p3 = (key + 3 <= qrow) ? exp2f(sacc[ntk][3]) : 0.f;
            } else {
                p0 = exp2f(sacc[ntk][0]);
                p1 = exp2f(sacc[ntk][1]);
                p2 = exp2f(sacc[ntk][2]);
                p3 = exp2f(sacc[ntk][3]);
            }
            uint2 pv;
            pv.x = pk_bf16(p0, p1);
            pv.y = pk_bf16(p2, p3);
            *(uint2*)&Pw[l15 * LDP + ntk * 16 + quad * 4] = pv;
        }

        // O += P V and l += P 1: V fragments from LDS; aP from wave-private P
        #pragma unroll
        for (int kkp = 0; kkp < 2; ++kkp) {
            bf16x8 aP = *(const bf16x8*)&Pw[l15 * LDP + kkp * 32 + quad * 8];
            #pragma unroll
            for (int dt = 0; dt < 4; ++dt) {
                bf16x8 bV = *(const bf16x8*)&Vv[(kkp * 4 + dt) * 512 + lane * 8];
                o[dt] = __builtin_amdgcn_mfma_f32_16x16x32_bf16(
                    aP, bV, o[dt], 0, 0, 0);
            }
            o_l = __builtin_amdgcn_mfma_f32_16x16x32_bf16(
                aP, vones, o_l, 0, 0, 0);
        }
        __syncthreads();   // all waves done reading Kv/Vv before next stage
    }

    if (!split) {
        // whole strip: normalize + store bf16 AO. o_l[r] is the denominator
        // for row quad*4+r (replicated across l15) -- no shuffles needed.
        float li[4];
        #pragma unroll
        for (int r = 0; r < 4; ++r)
            li[r] = 1.0f / o_l[r];
        #pragma unroll
        for (int dt = 0; dt < 4; ++dt)
            #pragma unroll
            for (int r = 0; r < 4; ++r)
                Op[(size_t)(quad * 4 + r) * D_MODEL + dt * 16 + l15] =
                    f2b(o[dt][r] * li[r]);
    } else {
        // split chunk: publish partials, take the pair ticket; the SECOND
        // block combines inline (own half still in registers).
        int pbase = ((bg * 16 + (q4 - 16)) * 4 + kq) * 2;   // even pair base
        int p = pbase + h;
        size_t obase = (size_t)(p * 4 + w) * 1024;
        #pragma unroll
        for (int dt = 0; dt < 4; ++dt)
            #pragma unroll
            for (int r = 0; r < 4; ++r)
                Opart[obase + (size_t)(quad * 4 + r) * 64 + dt * 16 + l15] =
                    o[dt][r];
        if (l15 == 0) {
            #pragma unroll
            for (int r = 0; r < 4; ++r)
                Lpart[(size_t)(p * 4 + w) * 16 + quad * 4 + r] = o_l[r];
        }
        // RELEASE: every thread fences its OWN stores, then the block
        // barrier guarantees all waves have stored+fenced BEFORE tid0
        // publishes the ticket.
        __threadfence();
        __syncthreads();
        if (tid == 0)
            ticket = atomicAdd(&flags[pbase >> 1], 1u);
        __syncthreads();
        if (ticket == 1u) {                      // we are second: combine
            __threadfence();                     // acquire other's partials
            int po = pbase + (1 - h);
            size_t ob2 = (size_t)(po * 4 + w) * 1024;
            #pragma unroll
            for (int dt = 0; dt < 4; ++dt)
                #pragma unroll
                for (int r = 0; r < 4; ++r)
                    o[dt][r] += Opart[ob2 + (size_t)(quad * 4 + r) * 64
                                      + dt * 16 + l15];
            float li[4];
            #pragma unroll
            for (int r = 0; r < 4; ++r)
                li[r] = 1.0f / (o_l[r] +
                        Lpart[(size_t)(po * 4 + w) * 16 + quad * 4 + r]);
            #pragma unroll
            for (int dt = 0; dt < 4; ++dt)
                #pragma unroll
                for (int r = 0; r < 4; ++r)
                    Op[(size_t)(quad * 4 + r) * D_MODEL + dt * 16 + l15] =
                        f2b(o[dt][r] * li[r]);
        }
    }
}

// ---------------------------------------------------------------------------
extern "C" void kernel_launch(void* const* d_in, const int* in_sizes, int n_in,
                              void* d_out, int out_size, void* d_ws, size_t ws_size,
                              hipStream_t stream) {
    const float* x  = (const float*)d_in[0];
    const float* Wq = (const float*)d_in[1];
    const float* bq = (const float*)d_in[2];
    const float* Wk = (const float*)d_in[3];
    const float* bk = (const float*)d_in[4];
    const float* Wv = (const float*)d_in[5];
    const float* bv = (const float*)d_in[6];
    const float* Wo = (const float*)d_in[7];
    const float* bo = (const float*)d_in[8];
    float* out = (float*)d_out;

    u16* ws    = (u16*)d_ws;
    u16* xb    = ws;  ws += (size_t)M_ROWS * 1024;   // x bf16; reused as AO
    u16* WcatT = ws;  ws += (size_t)QKV_N * 1024;
    u16* WoT   = ws;  ws += 1024 * 1024;
    u16* Qb    = ws;  ws += (size_t)M_ROWS * 1024;
    u16* Kpack = ws;  ws += (size_t)M_ROWS * KV_DIM;
    u16* Vpack = ws;  ws += (size_t)M_ROWS * KV_DIM;
    float* Opart = (float*)ws;                        // 1024*4*1024 f32 = 16.8MB
    float* Lpart = Opart + (size_t)1024 * 4 * 1024;   // 1024*4*16 f32 = 256KB
    unsigned int* flags = (unsigned int*)(Lpart + (size_t)1024 * 4 * 16); // 512 u32
    u16* AO    = xb;                                  // alias: xb dead after gemm_qkv
    // total ws use: ~43 MB

    prep<<<2048 + 2560 + 1, 256, 0, stream>>>(x, Wq, Wk, Wv, Wo, xb, WcatT, WoT,
                                              flags);
    gemm_qkv<<<dim3(QKV_N / 128, M_ROWS / 64), 256, 0, stream>>>(
        xb, WcatT, bq, bk, bv, Qb, Kpack, Vpack);
    attn_kernel<<<1536, 256, 0, stream>>>(Qb, Kpack, Vpack, AO, Opart, Lpart,
                                          flags);
    gemm_out<<<dim3(1024 / 128, M_ROWS / 64), 256, 0, stream>>>(AO, WoT, bo, out);
}

// Round 15
// 172.677 us; speedup vs baseline: 2.2403x; 2.2403x over previous
//
#include <hip/hip_runtime.h>
#include <hip/hip_bf16.h>
#include <stdint.h>

// Problem constants (GQA: D=1024, 16 heads, 4 groups, hd=64)
#define D_MODEL 1024
#define T_LEN   2048
#define BATCH   2
#define N_HEADS 16
#define KV_DIM  256
#define QKV_N   1536              // 1024 + 256 + 256 fused projection width
#define M_ROWS  (BATCH * T_LEN)   // 4096

typedef unsigned short u16;
typedef __bf16 bf16x8 __attribute__((ext_vector_type(8)));
typedef __bf16 bf16x2 __attribute__((ext_vector_type(2)));
typedef float  f32x4  __attribute__((ext_vector_type(4)));
typedef uint32_t u32x4v __attribute__((ext_vector_type(4)));

__device__ __forceinline__ u16 f2b(float f) {
    uint32_t u = __builtin_bit_cast(uint32_t, f);
    u += 0x7FFFu + ((u >> 16) & 1u);   // round-to-nearest-even
    return (u16)(u >> 16);
}

// pack two f32 -> two bf16 in one u32 (lo = a, hi = b)
__device__ __forceinline__ uint32_t pk_bf16(float a, float b) {
#if __has_builtin(__builtin_amdgcn_cvt_pk_bf16_f32)
    bf16x2 v = __builtin_amdgcn_cvt_pk_bf16_f32(a, b);
    return __builtin_bit_cast(uint32_t, v);
#else
    return (uint32_t)f2b(a) | ((uint32_t)f2b(b) << 16);
#endif
}

// async global->LDS, 16B per lane; LDS dest = wave-uniform base + lane*16
__device__ __forceinline__ void gl_lds16(const void* g, void* l) {
    __builtin_amdgcn_global_load_lds(g, l, 16, 0, 0);
}

// Chunk table: 48 entries, LPT-ish order, boustrophedon within length tiers
// so per-CU totals balance. Encoding: value<32 -> whole strip q4=value;
// else split chunk q4=value>>1, h=value&1 (h0=[0,ceil), h1=[ceil,q4+1)).
__constant__ unsigned char LPT_TBL[48] = {
    62, 63, 60, 15, 61, 58, 59, 56,     // L=16,16,16,16,15,15,15,15
    50, 53, 13, 52, 55, 54, 57, 14,     // L=13,13,14,14,14,14,14,15 (rev)
    51, 48, 12, 49, 46, 47, 44, 11,     // L=13,13,13,12,12,12,12,12
    39, 38, 41, 10, 40, 43, 42, 45,     // L=10,10,10,11,11,11,11,11 (rev)
    36,  9, 37, 34, 35, 32,  8, 33,     // L=10,10,9,9,9,9,9,8
     0,  1,  2,  3,  4,  5,  6,  7      // L=1..8 (rev)
};

// ---------------------------------------------------------------------------
// prep: fp32->bf16 convert of x (blocks 0..2047) + all-weight transpose/cvt
// (blocks 2048..4607). One launch.
// ---------------------------------------------------------------------------
__global__ __launch_bounds__(256) void prep(
    const float* __restrict__ x,
    const float* __restrict__ Wq, const float* __restrict__ Wk,
    const float* __restrict__ Wv, const float* __restrict__ Wo,
    u16* __restrict__ xb, u16* __restrict__ WcatT, u16* __restrict__ WoT)
{
    __shared__ u16 tile[32][33];
    int id = blockIdx.x;
    int tid = threadIdx.x;
    if (id < 2048) {
        int i = (id * 256 + tid) * 8;
        float4 a = *(const float4*)&x[i];
        float4 c = *(const float4*)&x[i + 4];
        u16 r[8] = { f2b(a.x), f2b(a.y), f2b(a.z), f2b(a.w),
                     f2b(c.x), f2b(c.y), f2b(c.z), f2b(c.w) };
        *(uint4*)&xb[i] = *(const uint4*)r;
        return;
    }
    int t = id - 2048;
    int bx = t % 80;
    int k0 = (t / 80) * 32;
    const float* src; u16* dst; int N, n0;
    if (bx < 32)       { src = Wq; dst = WcatT;                   N = 1024; n0 = bx * 32; }
    else if (bx < 40)  { src = Wk; dst = WcatT + 1024 * 1024;     N = 256;  n0 = (bx - 32) * 32; }
    else if (bx < 48)  { src = Wv; dst = WcatT + 1280 * 1024;     N = 256;  n0 = (bx - 40) * 32; }
    else               { src = Wo; dst = WoT;                     N = 1024; n0 = (bx - 48) * 32; }
    for (int i = 0; i < 4; ++i) {
        int idx = tid + i * 256;
        int r = idx >> 5, c = idx & 31;
        tile[r][c] = f2b(src[(size_t)(k0 + r) * N + (n0 + c)]);
    }
    __syncthreads();
    for (int i = 0; i < 4; ++i) {
        int idx = tid + i * 256;
        int r = idx >> 5, c = idx & 31;   // r: n-local, c: k-local
        dst[(size_t)(n0 + r) * 1024 + (k0 + c)] = tile[c][r];
    }
}

// ---------------------------------------------------------------------------
// Fused QKV GEMM, 64x128 tile, 4 waves, SINGLE-BUFFERED (round-8 proven
// form; 8-wave, dbuf, and 128x128 variants all measured neutral/negative).
// 768 blocks = 3/CU. Q -> Qb[4096x1024] PRE-SCALED (log2 domain).
// K -> Kpack, V -> Vpack: FRAGMENT-MAJOR layouts:
//   Kpack[(b,g)][t64][kk][ntk][lane=quad*16+l15][8e]
//       = K[key = t64*64+ntk*16+l15][d = kk*32+quad*8+e]
//   Vpack[(b,g)][t64][kkp][dt][lane=quad*16+l15][8e]
//       = V[key = t64*64+kkp*32+quad*8+e][d = dt*16+l15]
// ---------------------------------------------------------------------------
__global__ __launch_bounds__(256) void gemm_qkv(
    const u16* __restrict__ A, const u16* __restrict__ BT,
    const float* __restrict__ bq, const float* __restrict__ bk,
    const float* __restrict__ bv, u16* __restrict__ Qb,
    u16* __restrict__ Kpack, u16* __restrict__ Vpack)
{
    constexpr int K = 1024;
    constexpr float SCALE = 0.125f * 1.44269504088896f;
    __shared__ __align__(16) u16 As[64 * 64];
    __shared__ __align__(16) u16 Bs[128 * 64];

    int tid  = threadIdx.x;
    int lane = tid & 63, w = tid >> 6;
    int quad = lane >> 4, l15 = lane & 15;
    int m0 = blockIdx.y * 64, n0 = blockIdx.x * 128;
    int lr = lane >> 3, lc = (lane & 7) * 8;

    f32x4 acc[4][2] = {};

    for (int k0 = 0; k0 < K; k0 += 64) {
        for (int t = 0; t < 2; ++t) {
            int rb = t * 32 + w * 8;
            gl_lds16(&A[(size_t)(m0 + rb + lr) * K + k0 + lc], &As[rb * 64]);
        }
        for (int t = 0; t < 4; ++t) {
            int rb = t * 32 + w * 8;
            gl_lds16(&BT[(size_t)(n0 + rb + lr) * K + k0 + lc], &Bs[rb * 64]);
        }
        __syncthreads();
        for (int kk = 0; kk < 64; kk += 32) {
            bf16x8 a[4], b[2];
            for (int i = 0; i < 4; ++i)
                a[i] = *(const bf16x8*)&As[(i * 16 + l15) * 64 + kk + quad * 8];
            for (int j = 0; j < 2; ++j)
                b[j] = *(const bf16x8*)&Bs[(w * 32 + j * 16 + l15) * 64 + kk + quad * 8];
            for (int i = 0; i < 4; ++i)
                for (int j = 0; j < 2; ++j)
                    acc[i][j] = __builtin_amdgcn_mfma_f32_16x16x32_bf16(
                        a[i], b[j], acc[i][j], 0, 0, 0);
        }
        __syncthreads();
    }

    for (int j = 0; j < 2; ++j) {
        int col = n0 + w * 32 + j * 16 + l15;
        float bj = (col < 1024) ? bq[col] : (col < 1280) ? bk[col - 1024] : bv[col - 1280];
        for (int i = 0; i < 4; ++i) {
            int rowb = m0 + i * 16 + quad * 4;       // 4 consecutive rows
            int bb = rowb >> 11, keyloc = rowb & 2047;
            int t64 = keyloc >> 6;
            if (col < 1024) {
                for (int r = 0; r < 4; ++r)
                    Qb[(size_t)(rowb + r) * 1024 + col] =
                        f2b((acc[i][j][r] + bj) * SCALE);
            } else if (col < 1280) {
                int d = col - 1024; int g = d >> 6; d &= 63;
                int kk = d >> 5, qd = (d >> 3) & 3, e = d & 7;
                int ntk = (keyloc >> 4) & 3, l15k = keyloc & 15;
                size_t base = ((((size_t)(bb * 4 + g) * 32 + t64) * 2 + kk) * 4
                               + ntk) * 512 + qd * 128 + l15k * 8 + e;
                for (int r = 0; r < 4; ++r)
                    Kpack[base + r * 8] = f2b(acc[i][j][r] + bj);
            } else {
                int d = col - 1280; int g = d >> 6; d &= 63;
                int dt = d >> 4, l15v = d & 15;
                int kkp = (keyloc >> 5) & 1, qv = (keyloc >> 3) & 3, e0 = keyloc & 7;
                u16 tmp[4];
                for (int r = 0; r < 4; ++r) tmp[r] = f2b(acc[i][j][r] + bj);
                size_t base = ((((size_t)(bb * 4 + g) * 32 + t64) * 2 + kkp) * 4
                               + dt) * 512 + (qv * 16 + l15v) * 8 + e0;
                *(uint64_t*)&Vpack[base] = *(const uint64_t*)tmp;
            }
        }
    }
}

// ---------------------------------------------------------------------------
// Out-proj GEMM, 64x128 tile, 4 waves, SINGLE-BUFFERED (round-8 form).
// out[M x 1024](fp32) = AO * WoT^T + bo. 512 blocks = 2/CU.
// ---------------------------------------------------------------------------
__global__ __launch_bounds__(256) void gemm_out(
    const u16* __restrict__ A, const u16* __restrict__ BT,
    const float* __restrict__ bias, float* __restrict__ C)
{
    constexpr int K = 1024, N = 1024;
    __shared__ __align__(16) u16 As[64 * 64];
    __shared__ __align__(16) u16 Bs[128 * 64];

    int tid  = threadIdx.x;
    int lane = tid & 63, w = tid >> 6;
    int quad = lane >> 4, l15 = lane & 15;
    int m0 = blockIdx.y * 64, n0 = blockIdx.x * 128;
    int lr = lane >> 3, lc = (lane & 7) * 8;

    f32x4 acc[4][2] = {};

    for (int k0 = 0; k0 < K; k0 += 64) {
        for (int t = 0; t < 2; ++t) {
            int rb = t * 32 + w * 8;
            gl_lds16(&A[(size_t)(m0 + rb + lr) * K + k0 + lc], &As[rb * 64]);
        }
        for (int t = 0; t < 4; ++t) {
            int rb = t * 32 + w * 8;
            gl_lds16(&BT[(size_t)(n0 + rb + lr) * K + k0 + lc], &Bs[rb * 64]);
        }
        __syncthreads();
        for (int kk = 0; kk < 64; kk += 32) {
            bf16x8 a[4], b[2];
            for (int i = 0; i < 4; ++i)
                a[i] = *(const bf16x8*)&As[(i * 16 + l15) * 64 + kk + quad * 8];
            for (int j = 0; j < 2; ++j)
                b[j] = *(const bf16x8*)&Bs[(w * 32 + j * 16 + l15) * 64 + kk + quad * 8];
            for (int i = 0; i < 4; ++i)
                for (int j = 0; j < 2; ++j)
                    acc[i][j] = __builtin_amdgcn_mfma_f32_16x16x32_bf16(
                        a[i], b[j], acc[i][j], 0, 0, 0);
        }
        __syncthreads();
    }

    for (int j = 0; j < 2; ++j) {
        int col = n0 + w * 32 + j * 16 + l15;
        float bj = bias[col];
        for (int i = 0; i < 4; ++i) {
            int rowb = m0 + i * 16 + quad * 4;
            for (int r = 0; r < 4; ++r)
                C[(size_t)(rowb + r) * N + col] = acc[i][j][r] + bj;
        }
    }
}

// ---------------------------------------------------------------------------
// Flash attention v12 (causal, GQA): chunked LPT structure + ONES-COLUMN
// MFMA softmax denominator (l = P.1 on the MFMA pipe, C-layout indexed by
// output row -> no shuffles). RESTORED round-10 best (174.8us total).
// Fused-combine experiments (rounds 11-14) concluded: device-scope
// __threadfence on gfx950 = L2 writeback/invalidate across XCDs -> wipes
// the L2-resident K/V for all running blocks (attn 46 -> 262us). The
// separate combine kernel's inter-kernel barrier provides coherence free.
// Structure: 1536 blocks = 6/CU co-resident, LPT chunk table, shared K/V
// LDS staging, split partials linearly additive (fixed-max log2 softmax).
// ---------------------------------------------------------------------------
__global__ __launch_bounds__(256, 6) void attn_kernel(
    const u16* __restrict__ Qb,     // [B*T, 1024] bf16, pre-scaled
    const u16* __restrict__ Kpack,  // fragment-packed K
    const u16* __restrict__ Vpack,  // fragment-packed V
    u16* __restrict__ AO,           // [B*T, 1024] bf16
    float* __restrict__ Opart,      // [1024 partials][4 heads][16 rows][64 d]
    float* __restrict__ Lpart)      // [1024 partials][4 heads][16 rows]
{
    constexpr int LDP = 72;   // P row stride (u16)
    __shared__ __align__(16) u16 Kv[4096];          // 8KB K tile, fragment-major
    __shared__ __align__(16) u16 Vv[4096];          // 8KB V tile, fragment-major
    __shared__ __align__(16) u16 Ps[4][16 * LDP];   // wave-private P tiles

    int tid  = threadIdx.x;
    int lane = tid & 63, w = tid >> 6;              // w = head within group
    int quad = lane >> 4, l15 = lane & 15;

    int gid = blockIdx.x;
    int bg = gid & 7;
    int b = bg >> 2, g = bg & 3;
    int idx = gid >> 3;                      // 0..191
    int code = LPT_TBL[idx >> 2];
    int kq = idx & 3;
    int q4, h = 0, tgB, tgE;
    bool split;
    if (code < 32) {
        split = false; q4 = code; tgB = 0; tgE = q4 + 1;
    } else {
        split = true; q4 = code >> 1; h = code & 1;
        int nA = (q4 + 2) >> 1;              // ceil((q4+1)/2)
        tgB = h ? nA : 0;
        tgE = h ? (q4 + 1) : nA;
    }
    int j = q4 * 4 + kq;
    int head = g * 4 + w;
    int q0 = j * 16;
    int iters64 = q4 + 1;                    // total 64-key tiles of strip

    const u16* Qp = Qb + ((size_t)b * T_LEN + q0) * 1024 + head * 64;
    const u16* Kp = Kpack + (size_t)bg * 131072;
    const u16* Vp = Vpack + (size_t)bg * 131072;
    u16*       Op = AO + ((size_t)b * T_LEN + q0) * D_MODEL + head * 64;
    u16* Pw = Ps[w];

    // Q fragments (loop-invariant): B-frag Q[n=qrow][k=d], 16 rows
    bf16x8 Qfrag[2];
    #pragma unroll
    for (int kk = 0; kk < 2; ++kk)
        Qfrag[kk] = *(const bf16x8*)&Qp[(size_t)l15 * 1024 + kk * 32 + quad * 8];

    // constant all-ones bf16 B-fragment for the denominator MFMA
    u32x4v onesbits = {0x3F803F80u, 0x3F803F80u, 0x3F803F80u, 0x3F803F80u};
    bf16x8 vones = __builtin_bit_cast(bf16x8, onesbits);

    f32x4 o[4] = {};
    f32x4 o_l = {};          // o_l[r] = softmax denom for row quad*4+r
    int qrow = q0 + l15;

    for (int tg = tgB; tg < tgE; ++tg) {
        bool diag = (tg == iters64 - 1);

        // stage K+V tiles (8KB each) into LDS once for all 4 heads.
        const u16* kt = Kp + (size_t)tg * 4096;
        const u16* vt = Vp + (size_t)tg * 4096;
        #pragma unroll
        for (int c = 0; c < 2; ++c) {
            int ch = w * 2 + c;                     // 0..7
            gl_lds16(kt + ch * 512 + lane * 8, &Kv[ch * 512]);
            gl_lds16(vt + ch * 512 + lane * 8, &Vv[ch * 512]);
        }
        __syncthreads();   // staging drained (implicit vmcnt(0))

        // S^T = K * Q^T; exp2; packed P -> wave-private LDS
        f32x4 sacc[4] = {};
        #pragma unroll
        for (int kk = 0; kk < 2; ++kk) {
            bf16x8 bQ = Qfrag[kk];
            #pragma unroll
            for (int ntk = 0; ntk < 4; ++ntk) {
                bf16x8 aK = *(const bf16x8*)&Kv[(kk * 4 + ntk) * 512 + lane * 8];
                sacc[ntk] = __builtin_amdgcn_mfma_f32_16x16x32_bf16(
                    aK, bQ, sacc[ntk], 0, 0, 0);
            }
        }
        #pragma unroll
        for (int ntk = 0; ntk < 4; ++ntk) {
            float p0, p1, p2, p3;
            if (diag) {
                int key = tg * 64 + ntk * 16 + quad * 4;
                p0 = (key + 0 <= qrow) ? exp2f(sacc[ntk][0]) : 0.f;
                p1 = (key + 1 <= qrow) ? exp2f(sacc[ntk][1]) : 0.f;
                p2 = (key + 2 <= qrow) ? exp2f(sacc[ntk][2]) : 0.f;
                p3 = (key + 3 <= qrow) ? exp2f(sacc[ntk][3]) : 0.f;
            } else {
                p0 = exp2f(sacc[ntk][0]);
                p1 = exp2f(sacc[ntk][1]);
                p2 = exp2f(sacc[ntk][2]);
                p3 = exp2f(sacc[ntk][3]);
            }
            uint2 pv;
            pv.x = pk_bf16(p0, p1);
            pv.y = pk_bf16(p2, p3);
            *(uint2*)&Pw[l15 * LDP + ntk * 16 + quad * 4] = pv;
        }

        // O += P V and l += P 1: V fragments from LDS; aP from wave-private P
        #pragma unroll
        for (int kkp = 0; kkp < 2; ++kkp) {
            bf16x8 aP = *(const bf16x8*)&Pw[l15 * LDP + kkp * 32 + quad * 8];
            #pragma unroll
            for (int dt = 0; dt < 4; ++dt) {
                bf16x8 bV = *(const bf16x8*)&Vv[(kkp * 4 + dt) * 512 + lane * 8];
                o[dt] = __builtin_amdgcn_mfma_f32_16x16x32_bf16(
                    aP, bV, o[dt], 0, 0, 0);
            }
            o_l = __builtin_amdgcn_mfma_f32_16x16x32_bf16(
                aP, vones, o_l, 0, 0, 0);
        }
        __syncthreads();   // all waves done reading Kv/Vv before next stage
    }

    if (!split) {
        // whole strip: normalize + store bf16 AO. o_l[r] is the denominator
        // for row quad*4+r (replicated across l15) -- no shuffles needed.
        float li[4];
        #pragma unroll
        for (int r = 0; r < 4; ++r)
            li[r] = 1.0f / o_l[r];
        #pragma unroll
        for (int dt = 0; dt < 4; ++dt)
            #pragma unroll
            for (int r = 0; r < 4; ++r)
                Op[(size_t)(quad * 4 + r) * D_MODEL + dt * 16 + l15] =
                    f2b(o[dt][r] * li[r]);
    } else {
        // split chunk: dump raw f32 partials (linearly additive, fixed-max)
        int p = ((bg * 16 + (q4 - 16)) * 4 + kq) * 2 + h;   // 0..1023
        size_t obase = (size_t)(p * 4 + w) * 1024;
        #pragma unroll
        for (int dt = 0; dt < 4; ++dt)
            #pragma unroll
            for (int r = 0; r < 4; ++r)
                Opart[obase + (size_t)(quad * 4 + r) * 64 + dt * 16 + l15] =
                    o[dt][r];
        if (l15 == 0) {
            #pragma unroll
            for (int r = 0; r < 4; ++r)
                Lpart[(size_t)(p * 4 + w) * 16 + quad * 4 + r] = o_l[r];
        }
    }
}

// ---------------------------------------------------------------------------
// attn_combine: for each split strip (q4 16..31) x head, sum the two
// partials, normalize, write bf16 AO. 2048 blocks x 64 threads.
// ---------------------------------------------------------------------------
__global__ __launch_bounds__(64) void attn_combine(
    const float* __restrict__ Opart, const float* __restrict__ Lpart,
    u16* __restrict__ AO)
{
    int gid = blockIdx.x;            // 0..2047
    int w  = gid & 3;
    int sp = gid >> 2;               // 0..511
    int bg = sp >> 6;
    int rest = sp & 63;
    int q4 = 16 + (rest >> 2);
    int kq = rest & 3;
    int b = bg >> 2, g = bg & 3;
    int head = g * 4 + w;
    int j = q4 * 4 + kq;
    int q0 = j * 16;
    int pA = ((bg * 16 + (q4 - 16)) * 4 + kq) * 2;

    const float* OA = Opart + (size_t)(pA * 4 + w) * 1024;
    const float* OB = Opart + (size_t)((pA + 1) * 4 + w) * 1024;
    const float* LA = Lpart + (size_t)(pA * 4 + w) * 16;
    const float* LB = Lpart + (size_t)((pA + 1) * 4 + w) * 16;

    int d = threadIdx.x;             // 0..63
    #pragma unroll 4
    for (int row = 0; row < 16; ++row) {
        float l = LA[row] + LB[row];
        float linv = 1.0f / l;
        float v = OA[row * 64 + d] + OB[row * 64 + d];
        AO[((size_t)(b * T_LEN + q0 + row)) * D_MODEL + head * 64 + d] =
            f2b(v * linv);
    }
}

// ---------------------------------------------------------------------------
extern "C" void kernel_launch(void* const* d_in, const int* in_sizes, int n_in,
                              void* d_out, int out_size, void* d_ws, size_t ws_size,
                              hipStream_t stream) {
    const float* x  = (const float*)d_in[0];
    const float* Wq = (const float*)d_in[1];
    const float* bq = (const float*)d_in[2];
    const float* Wk = (const float*)d_in[3];
    const float* bk = (const float*)d_in[4];
    const float* Wv = (const float*)d_in[5];
    const float* bv = (const float*)d_in[6];
    const float* Wo = (const float*)d_in[7];
    const float* bo = (const float*)d_in[8];
    float* out = (float*)d_out;

    u16* ws    = (u16*)d_ws;
    u16* xb    = ws;  ws += (size_t)M_ROWS * 1024;   // x bf16; reused as AO
    u16* WcatT = ws;  ws += (size_t)QKV_N * 1024;
    u16* WoT   = ws;  ws += 1024 * 1024;
    u16* Qb    = ws;  ws += (size_t)M_ROWS * 1024;
    u16* Kpack = ws;  ws += (size_t)M_ROWS * KV_DIM;
    u16* Vpack = ws;  ws += (size_t)M_ROWS * KV_DIM;
    float* Opart = (float*)ws;                        // 1024*4*1024 f32 = 16.8MB
    float* Lpart = Opart + (size_t)1024 * 4 * 1024;   // 1024*4*16 f32 = 256KB
    u16* AO    = xb;                                  // alias: xb dead after gemm_qkv
    // total ws use: ~43 MB

    prep<<<2048 + 2560, 256, 0, stream>>>(x, Wq, Wk, Wv, Wo, xb, WcatT, WoT);
    gemm_qkv<<<dim3(QKV_N / 128, M_ROWS / 64), 256, 0, stream>>>(
        xb, WcatT, bq, bk, bv, Qb, Kpack, Vpack);
    attn_kernel<<<1536, 256, 0, stream>>>(Qb, Kpack, Vpack, AO, Opart, Lpart);
    attn_combine<<<2048, 64, 0, stream>>>(Opart, Lpart, AO);
    gemm_out<<<dim3(1024 / 128, M_ROWS / 64), 256, 0, stream>>>(AO, WoT, bo, out);
}

// Round 16
// 169.167 us; speedup vs baseline: 2.2868x; 1.0207x over previous
//
#include <hip/hip_runtime.h>
#include <hip/hip_bf16.h>
#include <stdint.h>

// Problem constants (GQA: D=1024, 16 heads, 4 groups, hd=64)
#define D_MODEL 1024
#define T_LEN   2048
#define BATCH   2
#define N_HEADS 16
#define KV_DIM  256
#define QKV_N   1536              // 1024 + 256 + 256 fused projection width
#define M_ROWS  (BATCH * T_LEN)   // 4096

typedef unsigned short u16;
typedef __bf16 bf16x8 __attribute__((ext_vector_type(8)));
typedef __bf16 bf16x2 __attribute__((ext_vector_type(2)));
typedef float  f32x4  __attribute__((ext_vector_type(4)));
typedef uint32_t u32x4v __attribute__((ext_vector_type(4)));

__device__ __forceinline__ u16 f2b(float f) {
    uint32_t u = __builtin_bit_cast(uint32_t, f);
    u += 0x7FFFu + ((u >> 16) & 1u);   // round-to-nearest-even
    return (u16)(u >> 16);
}

// pack two f32 -> two bf16 in one u32 (lo = a, hi = b)
__device__ __forceinline__ uint32_t pk_bf16(float a, float b) {
#if __has_builtin(__builtin_amdgcn_cvt_pk_bf16_f32)
    bf16x2 v = __builtin_amdgcn_cvt_pk_bf16_f32(a, b);
    return __builtin_bit_cast(uint32_t, v);
#else
    return (uint32_t)f2b(a) | ((uint32_t)f2b(b) << 16);
#endif
}

// async global->LDS, 16B per lane; LDS dest = wave-uniform base + lane*16
__device__ __forceinline__ void gl_lds16(const void* g, void* l) {
    __builtin_amdgcn_global_load_lds(g, l, 16, 0, 0);
}

// Chunk table: 48 entries, LPT-ish order, boustrophedon within length tiers
// so per-CU totals balance. Encoding: value<32 -> whole strip q4=value;
// else split chunk q4=value>>1, h=value&1 (h0=[0,ceil), h1=[ceil,q4+1)).
__constant__ unsigned char LPT_TBL[48] = {
    62, 63, 60, 15, 61, 58, 59, 56,     // L=16,16,16,16,15,15,15,15
    50, 53, 13, 52, 55, 54, 57, 14,     // L=13,13,14,14,14,14,14,15 (rev)
    51, 48, 12, 49, 46, 47, 44, 11,     // L=13,13,13,12,12,12,12,12
    39, 38, 41, 10, 40, 43, 42, 45,     // L=10,10,10,11,11,11,11,11 (rev)
    36,  9, 37, 34, 35, 32,  8, 33,     // L=10,10,9,9,9,9,9,8
     0,  1,  2,  3,  4,  5,  6,  7      // L=1..8 (rev)
};

// ---------------------------------------------------------------------------
// prep: fp32->bf16 convert of x (blocks 0..2047) + all-weight transpose/cvt
// (blocks 2048..4607). One launch. (unchanged from round-15 best)
// ---------------------------------------------------------------------------
__global__ __launch_bounds__(256) void prep(
    const float* __restrict__ x,
    const float* __restrict__ Wq, const float* __restrict__ Wk,
    const float* __restrict__ Wv, const float* __restrict__ Wo,
    u16* __restrict__ xb, u16* __restrict__ WcatT, u16* __restrict__ WoT)
{
    __shared__ u16 tile[32][33];
    int id = blockIdx.x;
    int tid = threadIdx.x;
    if (id < 2048) {
        int i = (id * 256 + tid) * 8;
        float4 a = *(const float4*)&x[i];
        float4 c = *(const float4*)&x[i + 4];
        u16 r[8] = { f2b(a.x), f2b(a.y), f2b(a.z), f2b(a.w),
                     f2b(c.x), f2b(c.y), f2b(c.z), f2b(c.w) };
        *(uint4*)&xb[i] = *(const uint4*)r;
        return;
    }
    int t = id - 2048;
    int bx = t % 80;
    int k0 = (t / 80) * 32;
    const float* src; u16* dst; int N, n0;
    if (bx < 32)       { src = Wq; dst = WcatT;                   N = 1024; n0 = bx * 32; }
    else if (bx < 40)  { src = Wk; dst = WcatT + 1024 * 1024;     N = 256;  n0 = (bx - 32) * 32; }
    else if (bx < 48)  { src = Wv; dst = WcatT + 1280 * 1024;     N = 256;  n0 = (bx - 40) * 32; }
    else               { src = Wo; dst = WoT;                     N = 1024; n0 = (bx - 48) * 32; }
    for (int i = 0; i < 4; ++i) {
        int idx = tid + i * 256;
        int r = idx >> 5, c = idx & 31;
        tile[r][c] = f2b(src[(size_t)(k0 + r) * N + (n0 + c)]);
    }
    __syncthreads();
    for (int i = 0; i < 4; ++i) {
        int idx = tid + i * 256;
        int r = idx >> 5, c = idx & 31;   // r: n-local, c: k-local
        dst[(size_t)(n0 + r) * 1024 + (k0 + c)] = tile[c][r];
    }
}

// ---------------------------------------------------------------------------
// Fused QKV GEMM, 64x128 tile, 4 waves, NOW BK=128: stage TWO 64-K
// sub-tiles per barrier pair (LDS 24->48KB, still 3 blocks/CU; grid
// unchanged 768 = 3/CU). Rationale: 8-wave was NEUTRAL (stall is a
// barrier -- extra waves wait too), dbuf NEGATIVE (paid VGPR/LDS); the
// untried axis is halving the DRAIN FREQUENCY at constant tile/grid/VGPR.
// Straight-line #pragma unroll over compile-time sub-tile index (no
// lambda -> no attn-v10 VGPR bloat).
// Q -> Qb[4096x1024] PRE-SCALED (log2 domain).
// K -> Kpack, V -> Vpack: FRAGMENT-MAJOR layouts:
//   Kpack[(b,g)][t64][kk][ntk][lane=quad*16+l15][8e]
//       = K[key = t64*64+ntk*16+l15][d = kk*32+quad*8+e]
//   Vpack[(b,g)][t64][kkp][dt][lane=quad*16+l15][8e]
//       = V[key = t64*64+kkp*32+quad*8+e][d = dt*16+l15]
// ---------------------------------------------------------------------------
__global__ __launch_bounds__(256) void gemm_qkv(
    const u16* __restrict__ A, const u16* __restrict__ BT,
    const float* __restrict__ bq, const float* __restrict__ bk,
    const float* __restrict__ bv, u16* __restrict__ Qb,
    u16* __restrict__ Kpack, u16* __restrict__ Vpack)
{
    constexpr int K = 1024;
    constexpr float SCALE = 0.125f * 1.44269504088896f;
    __shared__ __align__(16) u16 As[2][64 * 64];    // 16 KB
    __shared__ __align__(16) u16 Bs[2][128 * 64];   // 32 KB

    int tid  = threadIdx.x;
    int lane = tid & 63, w = tid >> 6;
    int quad = lane >> 4, l15 = lane & 15;
    int m0 = blockIdx.y * 64, n0 = blockIdx.x * 128;
    int lr = lane >> 3, lc = (lane & 7) * 8;

    f32x4 acc[4][2] = {};

    for (int k0 = 0; k0 < K; k0 += 128) {
        #pragma unroll
        for (int s = 0; s < 2; ++s) {
            int kb = k0 + s * 64;
            for (int t = 0; t < 2; ++t) {
                int rb = t * 32 + w * 8;
                gl_lds16(&A[(size_t)(m0 + rb + lr) * K + kb + lc], &As[s][rb * 64]);
            }
            for (int t = 0; t < 4; ++t) {
                int rb = t * 32 + w * 8;
                gl_lds16(&BT[(size_t)(n0 + rb + lr) * K + kb + lc], &Bs[s][rb * 64]);
            }
        }
        __syncthreads();
        #pragma unroll
        for (int s = 0; s < 2; ++s) {
            for (int kk = 0; kk < 64; kk += 32) {
                bf16x8 a[4], b[2];
                for (int i = 0; i < 4; ++i)
                    a[i] = *(const bf16x8*)&As[s][(i * 16 + l15) * 64 + kk + quad * 8];
                for (int j = 0; j < 2; ++j)
                    b[j] = *(const bf16x8*)&Bs[s][(w * 32 + j * 16 + l15) * 64 + kk + quad * 8];
                for (int i = 0; i < 4; ++i)
                    for (int j = 0; j < 2; ++j)
                        acc[i][j] = __builtin_amdgcn_mfma_f32_16x16x32_bf16(
                            a[i], b[j], acc[i][j], 0, 0, 0);
            }
        }
        __syncthreads();
    }

    for (int j = 0; j < 2; ++j) {
        int col = n0 + w * 32 + j * 16 + l15;
        float bj = (col < 1024) ? bq[col] : (col < 1280) ? bk[col - 1024] : bv[col - 1280];
        for (int i = 0; i < 4; ++i) {
            int rowb = m0 + i * 16 + quad * 4;       // 4 consecutive rows
            int bb = rowb >> 11, keyloc = rowb & 2047;
            int t64 = keyloc >> 6;
            if (col < 1024) {
                for (int r = 0; r < 4; ++r)
                    Qb[(size_t)(rowb + r) * 1024 + col] =
                        f2b((acc[i][j][r] + bj) * SCALE);
            } else if (col < 1280) {
                int d = col - 1024; int g = d >> 6; d &= 63;
                int kk = d >> 5, qd = (d >> 3) & 3, e = d & 7;
                int ntk = (keyloc >> 4) & 3, l15k = keyloc & 15;
                size_t base = ((((size_t)(bb * 4 + g) * 32 + t64) * 2 + kk) * 4
                               + ntk) * 512 + qd * 128 + l15k * 8 + e;
                for (int r = 0; r < 4; ++r)
                    Kpack[base + r * 8] = f2b(acc[i][j][r] + bj);
            } else {
                int d = col - 1280; int g = d >> 6; d &= 63;
                int dt = d >> 4, l15v = d & 15;
                int kkp = (keyloc >> 5) & 1, qv = (keyloc >> 3) & 3, e0 = keyloc & 7;
                u16 tmp[4];
                for (int r = 0; r < 4; ++r) tmp[r] = f2b(acc[i][j][r] + bj);
                size_t base = ((((size_t)(bb * 4 + g) * 32 + t64) * 2 + kkp) * 4
                               + dt) * 512 + (qv * 16 + l15v) * 8 + e0;
                *(uint64_t*)&Vpack[base] = *(const uint64_t*)tmp;
            }
        }
    }
}

// ---------------------------------------------------------------------------
// Out-proj GEMM, 64x128 tile, 4 waves, BK=128 (same restructure).
// out[M x 1024](fp32) = AO * WoT^T + bo. 512 blocks = 2/CU.
// ---------------------------------------------------------------------------
__global__ __launch_bounds__(256) void gemm_out(
    const u16* __restrict__ A, const u16* __restrict__ BT,
    const float* __restrict__ bias, float* __restrict__ C)
{
    constexpr int K = 1024, N = 1024;
    __shared__ __align__(16) u16 As[2][64 * 64];
    __shared__ __align__(16) u16 Bs[2][128 * 64];

    int tid  = threadIdx.x;
    int lane = tid & 63, w = tid >> 6;
    int quad = lane >> 4, l15 = lane & 15;
    int m0 = blockIdx.y * 64, n0 = blockIdx.x * 128;
    int lr = lane >> 3, lc = (lane & 7) * 8;

    f32x4 acc[4][2] = {};

    for (int k0 = 0; k0 < K; k0 += 128) {
        #pragma unroll
        for (int s = 0; s < 2; ++s) {
            int kb = k0 + s * 64;
            for (int t = 0; t < 2; ++t) {
                int rb = t * 32 + w * 8;
                gl_lds16(&A[(size_t)(m0 + rb + lr) * K + kb + lc], &As[s][rb * 64]);
            }
            for (int t = 0; t < 4; ++t) {
                int rb = t * 32 + w * 8;
                gl_lds16(&BT[(size_t)(n0 + rb + lr) * K + kb + lc], &Bs[s][rb * 64]);
            }
        }
        __syncthreads();
        #pragma unroll
        for (int s = 0; s < 2; ++s) {
            for (int kk = 0; kk < 64; kk += 32) {
                bf16x8 a[4], b[2];
                for (int i = 0; i < 4; ++i)
                    a[i] = *(const bf16x8*)&As[s][(i * 16 + l15) * 64 + kk + quad * 8];
                for (int j = 0; j < 2; ++j)
                    b[j] = *(const bf16x8*)&Bs[s][(w * 32 + j * 16 + l15) * 64 + kk + quad * 8];
                for (int i = 0; i < 4; ++i)
                    for (int j = 0; j < 2; ++j)
                        acc[i][j] = __builtin_amdgcn_mfma_f32_16x16x32_bf16(
                            a[i], b[j], acc[i][j], 0, 0, 0);
            }
        }
        __syncthreads();
    }

    for (int j = 0; j < 2; ++j) {
        int col = n0 + w * 32 + j * 16 + l15;
        float bj = bias[col];
        for (int i = 0; i < 4; ++i) {
            int rowb = m0 + i * 16 + quad * 4;
            for (int r = 0; r < 4; ++r)
                C[(size_t)(rowb + r) * N + col] = acc[i][j][r] + bj;
        }
    }
}

// ---------------------------------------------------------------------------
// Flash attention v12 (causal, GQA): chunked LPT structure + ONES-COLUMN
// MFMA softmax denominator. UNCHANGED from round-15 best (172.7us total).
// Fused-combine experiments (rounds 11-14) concluded: device-scope
// __threadfence on gfx950 = L2 writeback/invalidate across XCDs -> wipes
// the L2-resident K/V for all running blocks (attn 46 -> 262us). The
// separate combine kernel's inter-kernel barrier provides coherence free.
// ---------------------------------------------------------------------------
__global__ __launch_bounds__(256, 6) void attn_kernel(
    const u16* __restrict__ Qb,     // [B*T, 1024] bf16, pre-scaled
    const u16* __restrict__ Kpack,  // fragment-packed K
    const u16* __restrict__ Vpack,  // fragment-packed V
    u16* __restrict__ AO,           // [B*T, 1024] bf16
    float* __restrict__ Opart,      // [1024 partials][4 heads][16 rows][64 d]
    float* __restrict__ Lpart)      // [1024 partials][4 heads][16 rows]
{
    constexpr int LDP = 72;   // P row stride (u16)
    __shared__ __align__(16) u16 Kv[4096];          // 8KB K tile, fragment-major
    __shared__ __align__(16) u16 Vv[4096];          // 8KB V tile, fragment-major
    __shared__ __align__(16) u16 Ps[4][16 * LDP];   // wave-private P tiles

    int tid  = threadIdx.x;
    int lane = tid & 63, w = tid >> 6;              // w = head within group
    int quad = lane >> 4, l15 = lane & 15;

    int gid = blockIdx.x;
    int bg = gid & 7;
    int b = bg >> 2, g = bg & 3;
    int idx = gid >> 3;                      // 0..191
    int code = LPT_TBL[idx >> 2];
    int kq = idx & 3;
    int q4, h = 0, tgB, tgE;
    bool split;
    if (code < 32) {
        split = false; q4 = code; tgB = 0; tgE = q4 + 1;
    } else {
        split = true; q4 = code >> 1; h = code & 1;
        int nA = (q4 + 2) >> 1;              // ceil((q4+1)/2)
        tgB = h ? nA : 0;
        tgE = h ? (q4 + 1) : nA;
    }
    int j = q4 * 4 + kq;
    int head = g * 4 + w;
    int q0 = j * 16;
    int iters64 = q4 + 1;                    // total 64-key tiles of strip

    const u16* Qp = Qb + ((size_t)b * T_LEN + q0) * 1024 + head * 64;
    const u16* Kp = Kpack + (size_t)bg * 131072;
    const u16* Vp = Vpack + (size_t)bg * 131072;
    u16*       Op = AO + ((size_t)b * T_LEN + q0) * D_MODEL + head * 64;
    u16* Pw = Ps[w];

    // Q fragments (loop-invariant): B-frag Q[n=qrow][k=d], 16 rows
    bf16x8 Qfrag[2];
    #pragma unroll
    for (int kk = 0; kk < 2; ++kk)
        Qfrag[kk] = *(const bf16x8*)&Qp[(size_t)l15 * 1024 + kk * 32 + quad * 8];

    // constant all-ones bf16 B-fragment for the denominator MFMA
    u32x4v onesbits = {0x3F803F80u, 0x3F803F80u, 0x3F803F80u, 0x3F803F80u};
    bf16x8 vones = __builtin_bit_cast(bf16x8, onesbits);

    f32x4 o[4] = {};
    f32x4 o_l = {};          // o_l[r] = softmax denom for row quad*4+r
    int qrow = q0 + l15;

    for (int tg = tgB; tg < tgE; ++tg) {
        bool diag = (tg == iters64 - 1);

        // stage K+V tiles (8KB each) into LDS once for all 4 heads.
        const u16* kt = Kp + (size_t)tg * 4096;
        const u16* vt = Vp + (size_t)tg * 4096;
        #pragma unroll
        for (int c = 0; c < 2; ++c) {
            int ch = w * 2 + c;                     // 0..7
            gl_lds16(kt + ch * 512 + lane * 8, &Kv[ch * 512]);
            gl_lds16(vt + ch * 512 + lane * 8, &Vv[ch * 512]);
        }
        __syncthreads();   // staging drained (implicit vmcnt(0))

        // S^T = K * Q^T; exp2; packed P -> wave-private LDS
        f32x4 sacc[4] = {};
        #pragma unroll
        for (int kk = 0; kk < 2; ++kk) {
            bf16x8 bQ = Qfrag[kk];
            #pragma unroll
            for (int ntk = 0; ntk < 4; ++ntk) {
                bf16x8 aK = *(const bf16x8*)&Kv[(kk * 4 + ntk) * 512 + lane * 8];
                sacc[ntk] = __builtin_amdgcn_mfma_f32_16x16x32_bf16(
                    aK, bQ, sacc[ntk], 0, 0, 0);
            }
        }
        #pragma unroll
        for (int ntk = 0; ntk < 4; ++ntk) {
            float p0, p1, p2, p3;
            if (diag) {
                int key = tg * 64 + ntk * 16 + quad * 4;
                p0 = (key + 0 <= qrow) ? exp2f(sacc[ntk][0]) : 0.f;
                p1 = (key + 1 <= qrow) ? exp2f(sacc[ntk][1]) : 0.f;
                p2 = (key + 2 <= qrow) ? exp2f(sacc[ntk][2]) : 0.f;
                p3 = (key + 3 <= qrow) ? exp2f(sacc[ntk][3]) : 0.f;
            } else {
                p0 = exp2f(sacc[ntk][0]);
                p1 = exp2f(sacc[ntk][1]);
                p2 = exp2f(sacc[ntk][2]);
                p3 = exp2f(sacc[ntk][3]);
            }
            uint2 pv;
            pv.x = pk_bf16(p0, p1);
            pv.y = pk_bf16(p2, p3);
            *(uint2*)&Pw[l15 * LDP + ntk * 16 + quad * 4] = pv;
        }

        // O += P V and l += P 1: V fragments from LDS; aP from wave-private P
        #pragma unroll
        for (int kkp = 0; kkp < 2; ++kkp) {
            bf16x8 aP = *(const bf16x8*)&Pw[l15 * LDP + kkp * 32 + quad * 8];
            #pragma unroll
            for (int dt = 0; dt < 4; ++dt) {
                bf16x8 bV = *(const bf16x8*)&Vv[(kkp * 4 + dt) * 512 + lane * 8];
                o[dt] = __builtin_amdgcn_mfma_f32_16x16x32_bf16(
                    aP, bV, o[dt], 0, 0, 0);
            }
            o_l = __builtin_amdgcn_mfma_f32_16x16x32_bf16(
                aP, vones, o_l, 0, 0, 0);
        }
        __syncthreads();   // all waves done reading Kv/Vv before next stage
    }

    if (!split) {
        // whole strip: normalize + store bf16 AO. o_l[r] is the denominator
        // for row quad*4+r (replicated across l15) -- no shuffles needed.
        float li[4];
        #pragma unroll
        for (int r = 0; r < 4; ++r)
            li[r] = 1.0f / o_l[r];
        #pragma unroll
        for (int dt = 0; dt < 4; ++dt)
            #pragma unroll
            for (int r = 0; r < 4; ++r)
                Op[(size_t)(quad * 4 + r) * D_MODEL + dt * 16 + l15] =
                    f2b(o[dt][r] * li[r]);
    } else {
        // split chunk: dump raw f32 partials (linearly additive, fixed-max)
        int p = ((bg * 16 + (q4 - 16)) * 4 + kq) * 2 + h;   // 0..1023
        size_t obase = (size_t)(p * 4 + w) * 1024;
        #pragma unroll
        for (int dt = 0; dt < 4; ++dt)
            #pragma unroll
            for (int r = 0; r < 4; ++r)
                Opart[obase + (size_t)(quad * 4 + r) * 64 + dt * 16 + l15] =
                    o[dt][r];
        if (l15 == 0) {
            #pragma unroll
            for (int r = 0; r < 4; ++r)
                Lpart[(size_t)(p * 4 + w) * 16 + quad * 4 + r] = o_l[r];
        }
    }
}

// ---------------------------------------------------------------------------
// attn_combine: for each split strip (q4 16..31) x head, sum the two
// partials, normalize, write bf16 AO. 2048 blocks x 64 threads. (unchanged)
// ---------------------------------------------------------------------------
__global__ __launch_bounds__(64) void attn_combine(
    const float* __restrict__ Opart, const float* __restrict__ Lpart,
    u16* __restrict__ AO)
{
    int gid = blockIdx.x;            // 0..2047
    int w  = gid & 3;
    int sp = gid >> 2;               // 0..511
    int bg = sp >> 6;
    int rest = sp & 63;
    int q4 = 16 + (rest >> 2);
    int kq = rest & 3;
    int b = bg >> 2, g = bg & 3;
    int head = g * 4 + w;
    int j = q4 * 4 + kq;
    int q0 = j * 16;
    int pA = ((bg * 16 + (q4 - 16)) * 4 + kq) * 2;

    const float* OA = Opart + (size_t)(pA * 4 + w) * 1024;
    const float* OB = Opart + (size_t)((pA + 1) * 4 + w) * 1024;
    const float* LA = Lpart + (size_t)(pA * 4 + w) * 16;
    const float* LB = Lpart + (size_t)((pA + 1) * 4 + w) * 16;

    int d = threadIdx.x;             // 0..63
    #pragma unroll 4
    for (int row = 0; row < 16; ++row) {
        float l = LA[row] + LB[row];
        float linv = 1.0f / l;
        float v = OA[row * 64 + d] + OB[row * 64 + d];
        AO[((size_t)(b * T_LEN + q0 + row)) * D_MODEL + head * 64 + d] =
            f2b(v * linv);
    }
}

// ---------------------------------------------------------------------------
extern "C" void kernel_launch(void* const* d_in, const int* in_sizes, int n_in,
                              void* d_out, int out_size, void* d_ws, size_t ws_size,
                              hipStream_t stream) {
    const float* x  = (const float*)d_in[0];
    const float* Wq = (const float*)d_in[1];
    const float* bq = (const float*)d_in[2];
    const float* Wk = (const float*)d_in[3];
    const float* bk = (const float*)d_in[4];
    const float* Wv = (const float*)d_in[5];
    const float* bv = (const float*)d_in[6];
    const float* Wo = (const float*)d_in[7];
    const float* bo = (const float*)d_in[8];
    float* out = (float*)d_out;

    u16* ws    = (u16*)d_ws;
    u16* xb    = ws;  ws += (size_t)M_ROWS * 1024;   // x bf16; reused as AO
    u16* WcatT = ws;  ws += (size_t)QKV_N * 1024;
    u16* WoT   = ws;  ws += 1024 * 1024;
    u16* Qb    = ws;  ws += (size_t)M_ROWS * 1024;
    u16* Kpack = ws;  ws += (size_t)M_ROWS * KV_DIM;
    u16* Vpack = ws;  ws += (size_t)M_ROWS * KV_DIM;
    float* Opart = (float*)ws;                        // 1024*4*1024 f32 = 16.8MB
    float* Lpart = Opart + (size_t)1024 * 4 * 1024;   // 1024*4*16 f32 = 256KB
    u16* AO    = xb;                                  // alias: xb dead after gemm_qkv
    // total ws use: ~43 MB

    prep<<<2048 + 2560, 256, 0, stream>>>(x, Wq, Wk, Wv, Wo, xb, WcatT, WoT);
    gemm_qkv<<<dim3(QKV_N / 128, M_ROWS / 64), 256, 0, stream>>>(
        xb, WcatT, bq, bk, bv, Qb, Kpack, Vpack);
    attn_kernel<<<1536, 256, 0, stream>>>(Qb, Kpack, Vpack, AO, Opart, Lpart);
    attn_combine<<<2048, 64, 0, stream>>>(Opart, Lpart, AO);
    gemm_out<<<dim3(1024 / 128, M_ROWS / 64), 256, 0, stream>>>(AO, WoT, bo, out);
}